// Round 16
// baseline (253.122 us; speedup 1.0000x reference)
//
#include <hip/hip_runtime.h>
#include <math.h>

// ---------------------------------------------------------------------------
// conv1 specialized: 3ch 1017x1017, 3x3 stride-2 conv + bias + relu + pool2.
// ---------------------------------------------------------------------------
__global__ __launch_bounds__(256) void conv1_lds(
    const float* __restrict__ in, const float* __restrict__ w,
    const float* __restrict__ bias, float* __restrict__ out)
{
    constexpr int Hin = 1017, P = 254;
    __shared__ float li[17][4][65];
    const int f  = blockIdx.y;
    const int ct = blockIdx.x & 3;
    const int rt = blockIdx.x >> 2;
    const int t  = threadIdx.x;
    const int lane = t & 63, wid = t >> 6;
    const int row0 = rt * 16, col0 = ct * 256;
    const float* inf = in + (size_t)f * 3 * Hin * Hin;

    const int ph = rt * 4 + wid, pw = ct * 64 + lane;
    const bool wactive = (ph < P) && (pw < P);

    float acc[32];
    #pragma unroll
    for (int i = 0; i < 32; i++) acc[i] = 0.f;

    for (int ic = 0; ic < 3; ic++) {
        __syncthreads();
        const float* src = inf + (size_t)ic * Hin * Hin;
        #pragma unroll
        for (int i = 0; i < 17; i++) {
            int gr = row0 + i; if (gr > Hin - 1) gr = Hin - 1;
            int gc = col0 + t; if (gc > Hin - 1) gc = Hin - 1;
            li[i][t & 3][t >> 2] = src[(size_t)gr * Hin + gc];
        }
        if (t < 17) {
            int gr = row0 + t; if (gr > Hin - 1) gr = Hin - 1;
            int gc = col0 + 256; if (gc > Hin - 1) gc = Hin - 1;
            li[t][0][64] = src[(size_t)gr * Hin + gc];
        }
        __syncthreads();

        float win[25];
        #pragma unroll
        for (int r = 0; r < 5; r++)
            #pragma unroll
            for (int c = 0; c < 5; c++)
                win[r * 5 + c] = li[4 * wid + r][c & 3][lane + (c >> 2)];

        #pragma unroll
        for (int oc = 0; oc < 8; oc++) {
            float wr[9];
            #pragma unroll
            for (int j = 0; j < 9; j++) wr[j] = w[(oc * 3 + ic) * 9 + j];
            #pragma unroll
            for (int py = 0; py < 2; py++)
                #pragma unroll
                for (int px = 0; px < 2; px++) {
                    float s = acc[(oc * 2 + py) * 2 + px];
                    #pragma unroll
                    for (int kh = 0; kh < 3; kh++)
                        #pragma unroll
                        for (int kw = 0; kw < 3; kw++)
                            s += wr[kh * 3 + kw] * win[(2 * py + kh) * 5 + (2 * px + kw)];
                    acc[(oc * 2 + py) * 2 + px] = s;
                }
        }
    }

    if (wactive) {
        #pragma unroll
        for (int oc = 0; oc < 8; oc++) {
            float m = fmaxf(fmaxf(acc[oc * 4 + 0], acc[oc * 4 + 1]),
                            fmaxf(acc[oc * 4 + 2], acc[oc * 4 + 3]));
            m = fmaxf(m + bias[oc], 0.f);
            out[(((size_t)f * 8 + oc) * P + ph) * P + pw] = m;
        }
    }
}

// ---------------------------------------------------------------------------
template<int IC, int OCG, bool RELU, bool FLATOUT>
__global__ __launch_bounds__(256) void conv_pool_s1(
    const float* __restrict__ in, const float* __restrict__ w,
    const float* __restrict__ bias, float* __restrict__ out,
    int Hin, int P, int OC)
{
    const int f = blockIdx.y, g = blockIdx.z;
    int tid = blockIdx.x * 256 + threadIdx.x;
    if (tid >= P * P) return;
    int ph = tid / P, pw = tid % P;
    const float* inf = in + ((size_t)f * IC) * Hin * Hin + (size_t)(2 * ph) * Hin + 2 * pw;
    const float* wg = w + (size_t)g * OCG * IC * 9;

    float acc[OCG * 4];
    #pragma unroll
    for (int i = 0; i < OCG * 4; i++) acc[i] = 0.f;

    for (int ic = 0; ic < IC; ic++) {
        const float* p = inf + (size_t)ic * Hin * Hin;
        float win[4][4];
        #pragma unroll
        for (int r = 0; r < 4; r++) {
            float2 a = *(const float2*)(p + (size_t)r * Hin);
            float2 b = *(const float2*)(p + (size_t)r * Hin + 2);
            win[r][0] = a.x; win[r][1] = a.y; win[r][2] = b.x; win[r][3] = b.y;
        }
        #pragma unroll
        for (int oc = 0; oc < OCG; oc++) {
            float wr[9];
            #pragma unroll
            for (int j = 0; j < 9; j++) wr[j] = wg[(oc * IC + ic) * 9 + j];
            #pragma unroll
            for (int py = 0; py < 2; py++)
                #pragma unroll
                for (int px = 0; px < 2; px++) {
                    float s = acc[(oc * 2 + py) * 2 + px];
                    #pragma unroll
                    for (int kh = 0; kh < 3; kh++)
                        #pragma unroll
                        for (int kw = 0; kw < 3; kw++)
                            s += wr[kh * 3 + kw] * win[py + kh][px + kw];
                    acc[(oc * 2 + py) * 2 + px] = s;
                }
        }
    }

    #pragma unroll
    for (int oc = 0; oc < OCG; oc++) {
        float m = fmaxf(fmaxf(acc[oc * 4 + 0], acc[oc * 4 + 1]),
                        fmaxf(acc[oc * 4 + 2], acc[oc * 4 + 3]));
        m += bias[g * OCG + oc];
        if (RELU) m = fmaxf(m, 0.f);
        int ocg = g * OCG + oc;
        if (FLATOUT) {
            out[(size_t)f * (P * P * OC) + (pw * P + ph) * OC + ocg] = m;
        } else {
            out[(((size_t)f * OC + ocg) * P + ph) * P + pw] = m;
        }
    }
}

// ---------------------------------------------------------------------------
__global__ __launch_bounds__(256) void fc_head_plus(
    const float* __restrict__ flat,
    const float* __restrict__ fc1w, const float* __restrict__ fc1b,
    const float* __restrict__ fc4w, const float* __restrict__ fc4b,
    const float* __restrict__ poses,
    const float* __restrict__ fc5w, const float* __restrict__ fc5b,
    float* __restrict__ shape20, float* __restrict__ pose200,
    float* __restrict__ pose_feat)
{
    int o = blockIdx.x;
    if (o < 220) {
        const float* W = (o < 20) ? fc1w + (size_t)o * 25088
                                  : fc4w + (size_t)(o - 20) * 25088;
        const float4* W4  = (const float4*)W;
        const float4* fl4 = (const float4*)flat;
        float acc[8];
        #pragma unroll
        for (int f = 0; f < 8; f++) acc[f] = 0.f;
        for (int i = threadIdx.x; i < 6272; i += 256) {
            float4 wv = W4[i];
            #pragma unroll
            for (int f = 0; f < 8; f++) {
                float4 xv = fl4[f * 6272 + i];
                acc[f] += wv.x * xv.x + wv.y * xv.y + wv.z * xv.z + wv.w * xv.w;
            }
        }
        #pragma unroll
        for (int f = 0; f < 8; f++)
            for (int off = 32; off > 0; off >>= 1)
                acc[f] += __shfl_down(acc[f], off, 64);
        __shared__ float red[4][8];
        int wid = threadIdx.x >> 6, lane = threadIdx.x & 63;
        if (lane == 0) {
            #pragma unroll
            for (int f = 0; f < 8; f++) red[wid][f] = acc[f];
        }
        __syncthreads();
        if (threadIdx.x < 8) {
            int f = threadIdx.x;
            float s = red[0][f] + red[1][f] + red[2][f] + red[3][f];
            if (o < 20) shape20[f * 20 + o] = s + fc1b[o];
            else        pose200[f * 200 + (o - 20)] = fmaxf(s + fc4b[o - 20], 0.f);
        }
    } else {
        int t = (o - 220) * 256 + threadIdx.x;
        if (t >= 8 * 200) return;
        int f = t / 200, oo = t % 200;
        float s = fc5b[oo];
        const float* pr = poses + f * 75;
        const float* wr = fc5w + oo * 75;
        #pragma unroll 5
        for (int j = 0; j < 75; j++) s += pr[j] * wr[j];
        pose_feat[f * 200 + oo] = fmaxf(s, 0.f);
    }
}

// ---------------------------------------------------------------------------
__global__ __launch_bounds__(256) void mid_fused(
    const float* __restrict__ shape20,
    const float* __restrict__ fc2w, const float* __restrict__ fc2b,
    const float* __restrict__ fc3w, const float* __restrict__ fc3b,
    float* __restrict__ x0, float* __restrict__ out,
    const float* __restrict__ pose200, const float* __restrict__ pose_feat,
    const float* __restrict__ fc6w, const float* __restrict__ fc6b,
    float* __restrict__ t1)
{
    int b = blockIdx.x, t = threadIdx.x;
    if (b < 216) {
        __shared__ float avr[20];
        if (t < 20) {
            float s = 0.f;
            for (int f = 0; f < 8; f++) s += shape20[f * 20 + t];
            avr[t] = s * 0.125f;
        }
        __syncthreads();
        int r = b * 256 + t;
        if (r < 55168) {
            float s = fc2b[r];
            const float4* w4 = (const float4*)(fc2w + (size_t)r * 20);
            #pragma unroll
            for (int q = 0; q < 5; q++) {
                float4 wv = w4[q];
                s += wv.x * avr[q * 4 + 0] + wv.y * avr[q * 4 + 1]
                   + wv.z * avr[q * 4 + 2] + wv.w * avr[q * 4 + 3];
            }
            x0[r] = s;
        }
        if (b == 0 && t < 10) {
            float s = fc3b[t];
            for (int j = 0; j < 20; j++) s += fc3w[t * 20 + j] * avr[j];
            out[20670 + t] = s;
        }
    } else {
        int wv = (b - 216) * 4 + (t >> 6);
        int lane = t & 63;
        if (wv >= 8 * 100) return;
        int f = wv / 100, o = wv % 100;
        float s = 0.f;
        for (int j = lane; j < 400; j += 64) {
            float xv = (j < 200) ? pose200[f * 200 + j] : pose_feat[f * 200 + (j - 200)];
            s += xv * fc6w[o * 400 + j];
        }
        #pragma unroll
        for (int off = 32; off > 0; off >>= 1) s += __shfl_down(s, off, 64);
        if (lane == 0) t1[f * 100 + o] = s + fc6b[o];
    }
}

// ---------------------------------------------------------------------------
__global__ __launch_bounds__(256) void fc7_gcl3(
    const float* __restrict__ x0, const int* __restrict__ ai3,
    const float* __restrict__ av3, const float* __restrict__ gW3,
    const float* __restrict__ gb3, float* __restrict__ y3,
    const float* __restrict__ t1, const float* __restrict__ fc7w,
    const float* __restrict__ fc7b, const float* __restrict__ pose_mean,
    const float* __restrict__ trans, float* __restrict__ out)
{
    constexpr int F = 64, O = 32, N = 862;
    __shared__ float h[256];
    __shared__ float pp[256];
    const int b = blockIdx.x;
    const int wid = threadIdx.x >> 6, lane = threadIdx.x & 63;

    if (b < N) {
        const int n = b;
        {
            const int k = wid;
            const int*   ip = ai3 + ((size_t)k * N + n) * 16;
            const float* vp = av3 + ((size_t)k * N + n) * 16;
            float s = 0.f;
            #pragma unroll
            for (int d = 0; d < 16; d++)
                s += vp[d] * x0[(size_t)ip[d] * F + lane];
            h[k * F + lane] = s;
        }
        __syncthreads();
        const int t = threadIdx.x;
        const int o = t & 31, part = t >> 5;
        {
            float s = 0.f;
            const int base = part * 32;
            #pragma unroll 8
            for (int i = 0; i < 32; i++)
                s += h[base + i] * gW3[(size_t)(base + i) * O + o];
            pp[t] = s;
        }
        __syncthreads();
        if (t < O) {
            float s = gb3[t];
            #pragma unroll
            for (int p = 0; p < 8; p++) s += pp[p * O + t];
            y3[(size_t)n * O + t] = fmaxf(s, 0.f);
        }
    } else {
        int wv = (b - N) * 4 + wid;
        if (wv >= 8 * 219) return;
        int f = wv / 219, c = wv % 219;
        float s = t1[f * 100 + lane] * fc7w[c * 100 + lane];
        int j2 = lane + 64;
        if (j2 < 100) s += t1[f * 100 + j2] * fc7w[c * 100 + j2];
        #pragma unroll
        for (int off = 32; off > 0; off >>= 1) s += __shfl_down(s, off, 64);
        if (lane != 0) return;
        s += fc7b[c];
        float pct;
        if (c < 3) {
            pct = trans[c];
        } else {
            int j = (c - 3) / 9, e = (c - 3) % 9;
            float rx = (j == 0) ? 0.f : pose_mean[3 * j + 0];
            float ry = (j == 0) ? 0.f : pose_mean[3 * j + 1];
            float rz = (j == 0) ? 0.f : pose_mean[3 * j + 2];
            float th = sqrtf(rx * rx + ry * ry + rz * rz) + 1e-8f;
            float kx = rx / th, ky = ry / th, kz = rz / th;
            float sn = sinf(th), c2 = 1.f - cosf(th);
            float R[9];
            R[0] = 1.f - c2 * (ky * ky + kz * kz);
            R[1] = -sn * kz + c2 * (kx * ky);
            R[2] =  sn * ky + c2 * (kx * kz);
            R[3] =  sn * kz + c2 * (kx * ky);
            R[4] = 1.f - c2 * (kx * kx + kz * kz);
            R[5] = -sn * kx + c2 * (ky * kz);
            R[6] = -sn * ky + c2 * (kx * kz);
            R[7] =  sn * kx + c2 * (ky * kz);
            R[8] = 1.f - c2 * (kx * kx + ky * ky);
            pct = R[e];
        }
        s += pct;
        if (c < 3) out[22408 + f * 3 + c] = s;
        else       out[20680 + f * 216 + (c - 3)] = s;
    }
}

// ---------------------------------------------------------------------------
template<int F, int O, int ACT>
__global__ __launch_bounds__(256) void gcl(
    const float* __restrict__ x, const int* __restrict__ ai,
    const float* __restrict__ av, const float* __restrict__ gW,
    const float* __restrict__ gb, float* __restrict__ y, int N)
{
    constexpr int VPB = 64 / F;
    constexpr int OUTS = VPB * O;
    constexpr int PARTS = (256 / OUTS) >= 16 ? 16 :
                          ((256 / OUTS) >= 8 ? 8 :
                          ((256 / OUTS) >= 4 ? 4 : 2));
    constexpr int CH = 4 * F / PARTS;
    constexpr int HS = 4 * F + 4;
    __shared__ float h[VPB][HS];
    __shared__ float pp[OUTS * PARTS];

    const int k = threadIdx.x >> 6;
    const int lane = threadIdx.x & 63;
    const int vl = (VPB == 1) ? 0 : lane / F;
    const int fl = lane % F;
    const int n = blockIdx.x * VPB + vl;
    if (n < N) {
        const int*   ip = ai + ((size_t)k * N + n) * 16;
        const float* vp = av + ((size_t)k * N + n) * 16;
        float s = 0.f;
        #pragma unroll
        for (int d = 0; d < 16; d++)
            s += vp[d] * x[(size_t)ip[d] * F + fl];
        h[vl][k * F + fl] = s;
    }
    __syncthreads();

    const int t = threadIdx.x;
    if (t < OUTS * PARTS) {
        const int idx = t % OUTS;
        const int part = t / OUTS;
        const int v = idx / O, o = idx % O;
        float s = 0.f;
        const int base = part * CH;
        #pragma unroll
        for (int i = 0; i < CH; i++)
            s += h[v][base + i] * gW[(size_t)(base + i) * O + o];
        pp[part * OUTS + idx] = s;
    }
    __syncthreads();
    if (t < OUTS) {
        const int v = t / O, o = t % O;
        const int n2 = blockIdx.x * VPB + v;
        if (n2 < N) {
            float s = gb[o];
            #pragma unroll
            for (int p = 0; p < PARTS; p++) s += pp[p * OUTS + t];
            if (ACT == 0) s = fmaxf(s, 0.f);
            else          s = tanhf(s) * 0.1f;
            y[(size_t)n2 * O + o] = s;
        }
    }
}

template<int F>
__global__ __launch_bounds__(256) void spmm(
    const float* __restrict__ x, const int* __restrict__ ui,
    const float* __restrict__ uv, float* __restrict__ y, int N)
{
    int t = blockIdx.x * 256 + threadIdx.x;
    if (t >= N * F) return;
    int n = t / F, f = t % F;
    float s = 0.f;
    #pragma unroll
    for (int j = 0; j < 4; j++)
        s += uv[n * 4 + j] * x[(size_t)ui[n * 4 + j] * F + f];
    y[t] = s;
}

// ---------------------------------------------------------------------------
// MEASUREMENT (this round): near-empty kernel; 50 launches read the per-
// dispatch floor directly: dur = base + 50*f. No loop -> no LICM artifact.
// ---------------------------------------------------------------------------
__global__ __launch_bounds__(64) void empty_probe(float* __restrict__ scratch, int i)
{
    if (threadIdx.x == 0 && blockIdx.x == 0) scratch[i] = (float)i;
}

// ---------------------------------------------------------------------------
extern "C" void kernel_launch(void* const* d_in, const int* in_sizes, int n_in,
                              void* d_out, int out_size, void* d_ws, size_t ws_size,
                              hipStream_t stream) {
    (void)in_sizes; (void)n_in; (void)out_size; (void)ws_size;

    const float* seg   = (const float*)d_in[0];
    const float* poses = (const float*)d_in[1];
    const float* pmean = (const float*)d_in[2];
    const float* trans = (const float*)d_in[3];
    const float* c1w = (const float*)d_in[4];  const float* c1b = (const float*)d_in[5];
    const float* c2w = (const float*)d_in[6];  const float* c2b = (const float*)d_in[7];
    const float* c3w = (const float*)d_in[8];  const float* c3b = (const float*)d_in[9];
    const float* c4w = (const float*)d_in[10]; const float* c4b = (const float*)d_in[11];
    const float* c5w = (const float*)d_in[12]; const float* c5b = (const float*)d_in[13];
    const float* fc1w = (const float*)d_in[14]; const float* fc1b = (const float*)d_in[15];
    const float* fc2w = (const float*)d_in[16]; const float* fc2b = (const float*)d_in[17];
    const float* fc3w = (const float*)d_in[18]; const float* fc3b = (const float*)d_in[19];
    const float* fc4w = (const float*)d_in[20]; const float* fc4b = (const float*)d_in[21];
    const float* fc5w = (const float*)d_in[22]; const float* fc5b = (const float*)d_in[23];
    const float* fc6w = (const float*)d_in[24]; const float* fc6b = (const float*)d_in[25];
    const float* fc7w = (const float*)d_in[26]; const float* fc7b = (const float*)d_in[27];
    const float* gW3 = (const float*)d_in[28]; const float* gb3 = (const float*)d_in[29];
    const float* gW2 = (const float*)d_in[30]; const float* gb2 = (const float*)d_in[31];
    const float* gW1 = (const float*)d_in[32]; const float* gb1 = (const float*)d_in[33];
    const float* gW0 = (const float*)d_in[34]; const float* gb0 = (const float*)d_in[35];
    const float* av3 = (const float*)d_in[36]; const int* ai3 = (const int*)d_in[37];
    const float* av2 = (const float*)d_in[38]; const int* ai2 = (const int*)d_in[39];
    const float* av1 = (const float*)d_in[40]; const int* ai1 = (const int*)d_in[41];
    const float* av0 = (const float*)d_in[42]; const int* ai0 = (const int*)d_in[43];
    const float* uv2 = (const float*)d_in[44]; const int* ui2 = (const int*)d_in[45];
    const float* uv1 = (const float*)d_in[46]; const int* ui1 = (const int*)d_in[47];
    const float* uv0 = (const float*)d_in[48]; const int* ui0 = (const int*)d_in[49];

    float* W = (float*)d_ws;
    float* out = (float*)d_out;

    float* pool1 = W + 0;
    float* pool2 = W + 4129024;
    float* pool3 = W + 0;
    float* pool4 = W + 4129024;
    float* flat5 = W + 4589824;
    float* shape20 = W + 1000000;
    float* pose200 = shape20 + 160;
    float* x0  = pose200 + 1600;
    float* y3  = x0 + 55168;
    float* x2  = y3 + 27584;
    float* y2  = x2 + 55136;
    float* x1  = y2 + 27568;
    float* y1  = x1 + 55120;
    float* x0u = y1 + 55120;
    float* pose_feat = x0u + 110240;
    float* t1 = pose_feat + 1600;
    float* probe = W + 6000000;

    // ---- real chain (identical to round 14, best = 169.9 us) ----
    conv1_lds<<<dim3(256, 8), 256, 0, stream>>>(seg, c1w, c1b, pool1);
    conv_pool_s1<8, 8, true, false>
        <<<dim3(63, 8, 2), 256, 0, stream>>>(pool1, c2w, c2b, pool2, 254, 126, 16);
    conv_pool_s1<16, 4, true, false>
        <<<dim3(16, 8, 8), 256, 0, stream>>>(pool2, c3w, c3b, pool3, 126, 62, 32);
    conv_pool_s1<32, 2, true, false>
        <<<dim3(4, 8, 32), 256, 0, stream>>>(pool3, c4w, c4b, pool4, 62, 30, 64);
    conv_pool_s1<64, 2, false, true>
        <<<dim3(1, 8, 64), 256, 0, stream>>>(pool4, c5w, c5b, flat5, 30, 14, 128);
    fc_head_plus<<<dim3(227), 256, 0, stream>>>(flat5, fc1w, fc1b, fc4w, fc4b,
                                                poses, fc5w, fc5b,
                                                shape20, pose200, pose_feat);
    mid_fused<<<dim3(416), 256, 0, stream>>>(shape20, fc2w, fc2b, fc3w, fc3b, x0, out,
                                             pose200, pose_feat, fc6w, fc6b, t1);
    fc7_gcl3<<<dim3(1300), 256, 0, stream>>>(x0, ai3, av3, gW3, gb3, y3,
                                             t1, fc7w, fc7b, pmean, trans, out);
    spmm<32>      <<<dim3(216),  256, 0, stream>>>(y3,  ui2, uv2, x2, 1723);
    gcl<32, 16, 0><<<dim3(862),  256, 0, stream>>>(x2,  ai2, av2, gW2, gb2, y2, 1723);
    spmm<16>      <<<dim3(216),  256, 0, stream>>>(y2,  ui1, uv1, x1, 3445);
    gcl<16, 16, 0><<<dim3(862),  256, 0, stream>>>(x1,  ai1, av1, gW1, gb1, y1, 3445);
    spmm<16>      <<<dim3(431),  256, 0, stream>>>(y1,  ui0, uv0, x0u, 6890);
    gcl<16, 3, 1> <<<dim3(1723), 256, 0, stream>>>(x0u, ai0, av0, gW0, gb0, out, 6890);

    // ---- dispatch-floor probe: 50 near-empty launches ----
    for (int i = 0; i < 50; ++i)
        empty_probe<<<dim3(1), 64, 0, stream>>>(probe, i);
}

// Round 17
// 165.956 us; speedup vs baseline: 1.5252x; 1.5252x over previous
//
#include <hip/hip_runtime.h>
#include <math.h>

// ---------------------------------------------------------------------------
// conv1 specialized: 3ch 1017x1017, 3x3 stride-2 conv + bias + relu + pool2.
// ---------------------------------------------------------------------------
__global__ __launch_bounds__(256) void conv1_lds(
    const float* __restrict__ in, const float* __restrict__ w,
    const float* __restrict__ bias, float* __restrict__ out)
{
    constexpr int Hin = 1017, P = 254;
    __shared__ float li[17][4][65];
    const int f  = blockIdx.y;
    const int ct = blockIdx.x & 3;
    const int rt = blockIdx.x >> 2;
    const int t  = threadIdx.x;
    const int lane = t & 63, wid = t >> 6;
    const int row0 = rt * 16, col0 = ct * 256;
    const float* inf = in + (size_t)f * 3 * Hin * Hin;

    const int ph = rt * 4 + wid, pw = ct * 64 + lane;
    const bool wactive = (ph < P) && (pw < P);

    float acc[32];
    #pragma unroll
    for (int i = 0; i < 32; i++) acc[i] = 0.f;

    for (int ic = 0; ic < 3; ic++) {
        __syncthreads();
        const float* src = inf + (size_t)ic * Hin * Hin;
        #pragma unroll
        for (int i = 0; i < 17; i++) {
            int gr = row0 + i; if (gr > Hin - 1) gr = Hin - 1;
            int gc = col0 + t; if (gc > Hin - 1) gc = Hin - 1;
            li[i][t & 3][t >> 2] = src[(size_t)gr * Hin + gc];
        }
        if (t < 17) {
            int gr = row0 + t; if (gr > Hin - 1) gr = Hin - 1;
            int gc = col0 + 256; if (gc > Hin - 1) gc = Hin - 1;
            li[t][0][64] = src[(size_t)gr * Hin + gc];
        }
        __syncthreads();

        float win[25];
        #pragma unroll
        for (int r = 0; r < 5; r++)
            #pragma unroll
            for (int c = 0; c < 5; c++)
                win[r * 5 + c] = li[4 * wid + r][c & 3][lane + (c >> 2)];

        #pragma unroll
        for (int oc = 0; oc < 8; oc++) {
            float wr[9];
            #pragma unroll
            for (int j = 0; j < 9; j++) wr[j] = w[(oc * 3 + ic) * 9 + j];
            #pragma unroll
            for (int py = 0; py < 2; py++)
                #pragma unroll
                for (int px = 0; px < 2; px++) {
                    float s = acc[(oc * 2 + py) * 2 + px];
                    #pragma unroll
                    for (int kh = 0; kh < 3; kh++)
                        #pragma unroll
                        for (int kw = 0; kw < 3; kw++)
                            s += wr[kh * 3 + kw] * win[(2 * py + kh) * 5 + (2 * px + kw)];
                    acc[(oc * 2 + py) * 2 + px] = s;
                }
        }
    }

    if (wactive) {
        #pragma unroll
        for (int oc = 0; oc < 8; oc++) {
            float m = fmaxf(fmaxf(acc[oc * 4 + 0], acc[oc * 4 + 1]),
                            fmaxf(acc[oc * 4 + 2], acc[oc * 4 + 3]));
            m = fmaxf(m + bias[oc], 0.f);
            out[(((size_t)f * 8 + oc) * P + ph) * P + pw] = m;
        }
    }
}

// ---------------------------------------------------------------------------
template<int IC, int OCG, bool RELU, bool FLATOUT>
__global__ __launch_bounds__(256) void conv_pool_s1(
    const float* __restrict__ in, const float* __restrict__ w,
    const float* __restrict__ bias, float* __restrict__ out,
    int Hin, int P, int OC)
{
    const int f = blockIdx.y, g = blockIdx.z;
    int tid = blockIdx.x * 256 + threadIdx.x;
    if (tid >= P * P) return;
    int ph = tid / P, pw = tid % P;
    const float* inf = in + ((size_t)f * IC) * Hin * Hin + (size_t)(2 * ph) * Hin + 2 * pw;
    const float* wg = w + (size_t)g * OCG * IC * 9;

    float acc[OCG * 4];
    #pragma unroll
    for (int i = 0; i < OCG * 4; i++) acc[i] = 0.f;

    for (int ic = 0; ic < IC; ic++) {
        const float* p = inf + (size_t)ic * Hin * Hin;
        float win[4][4];
        #pragma unroll
        for (int r = 0; r < 4; r++) {
            float2 a = *(const float2*)(p + (size_t)r * Hin);
            float2 b = *(const float2*)(p + (size_t)r * Hin + 2);
            win[r][0] = a.x; win[r][1] = a.y; win[r][2] = b.x; win[r][3] = b.y;
        }
        #pragma unroll
        for (int oc = 0; oc < OCG; oc++) {
            float wr[9];
            #pragma unroll
            for (int j = 0; j < 9; j++) wr[j] = wg[(oc * IC + ic) * 9 + j];
            #pragma unroll
            for (int py = 0; py < 2; py++)
                #pragma unroll
                for (int px = 0; px < 2; px++) {
                    float s = acc[(oc * 2 + py) * 2 + px];
                    #pragma unroll
                    for (int kh = 0; kh < 3; kh++)
                        #pragma unroll
                        for (int kw = 0; kw < 3; kw++)
                            s += wr[kh * 3 + kw] * win[py + kh][px + kw];
                    acc[(oc * 2 + py) * 2 + px] = s;
                }
        }
    }

    #pragma unroll
    for (int oc = 0; oc < OCG; oc++) {
        float m = fmaxf(fmaxf(acc[oc * 4 + 0], acc[oc * 4 + 1]),
                        fmaxf(acc[oc * 4 + 2], acc[oc * 4 + 3]));
        m += bias[g * OCG + oc];
        if (RELU) m = fmaxf(m, 0.f);
        int ocg = g * OCG + oc;
        if (FLATOUT) {
            out[(size_t)f * (P * P * OC) + (pw * P + ph) * OC + ocg] = m;
        } else {
            out[(((size_t)f * OC + ocg) * P + ph) * P + pw] = m;
        }
    }
}

// ---------------------------------------------------------------------------
__global__ __launch_bounds__(256) void fc_head_plus(
    const float* __restrict__ flat,
    const float* __restrict__ fc1w, const float* __restrict__ fc1b,
    const float* __restrict__ fc4w, const float* __restrict__ fc4b,
    const float* __restrict__ poses,
    const float* __restrict__ fc5w, const float* __restrict__ fc5b,
    float* __restrict__ shape20, float* __restrict__ pose200,
    float* __restrict__ pose_feat)
{
    int o = blockIdx.x;
    if (o < 220) {
        const float* W = (o < 20) ? fc1w + (size_t)o * 25088
                                  : fc4w + (size_t)(o - 20) * 25088;
        const float4* W4  = (const float4*)W;
        const float4* fl4 = (const float4*)flat;
        float acc[8];
        #pragma unroll
        for (int f = 0; f < 8; f++) acc[f] = 0.f;
        for (int i = threadIdx.x; i < 6272; i += 256) {
            float4 wv = W4[i];
            #pragma unroll
            for (int f = 0; f < 8; f++) {
                float4 xv = fl4[f * 6272 + i];
                acc[f] += wv.x * xv.x + wv.y * xv.y + wv.z * xv.z + wv.w * xv.w;
            }
        }
        #pragma unroll
        for (int f = 0; f < 8; f++)
            for (int off = 32; off > 0; off >>= 1)
                acc[f] += __shfl_down(acc[f], off, 64);
        __shared__ float red[4][8];
        int wid = threadIdx.x >> 6, lane = threadIdx.x & 63;
        if (lane == 0) {
            #pragma unroll
            for (int f = 0; f < 8; f++) red[wid][f] = acc[f];
        }
        __syncthreads();
        if (threadIdx.x < 8) {
            int f = threadIdx.x;
            float s = red[0][f] + red[1][f] + red[2][f] + red[3][f];
            if (o < 20) shape20[f * 20 + o] = s + fc1b[o];
            else        pose200[f * 200 + (o - 20)] = fmaxf(s + fc4b[o - 20], 0.f);
        }
    } else {
        int t = (o - 220) * 256 + threadIdx.x;
        if (t >= 8 * 200) return;
        int f = t / 200, oo = t % 200;
        float s = fc5b[oo];
        const float* pr = poses + f * 75;
        const float* wr = fc5w + oo * 75;
        #pragma unroll 5
        for (int j = 0; j < 75; j++) s += pr[j] * wr[j];
        pose_feat[f * 200 + oo] = fmaxf(s, 0.f);
    }
}

// ---------------------------------------------------------------------------
__global__ __launch_bounds__(256) void mid_fused(
    const float* __restrict__ shape20,
    const float* __restrict__ fc2w, const float* __restrict__ fc2b,
    const float* __restrict__ fc3w, const float* __restrict__ fc3b,
    float* __restrict__ x0, float* __restrict__ out,
    const float* __restrict__ pose200, const float* __restrict__ pose_feat,
    const float* __restrict__ fc6w, const float* __restrict__ fc6b,
    float* __restrict__ t1)
{
    int b = blockIdx.x, t = threadIdx.x;
    if (b < 216) {
        __shared__ float avr[20];
        if (t < 20) {
            float s = 0.f;
            for (int f = 0; f < 8; f++) s += shape20[f * 20 + t];
            avr[t] = s * 0.125f;
        }
        __syncthreads();
        int r = b * 256 + t;
        if (r < 55168) {
            float s = fc2b[r];
            const float4* w4 = (const float4*)(fc2w + (size_t)r * 20);
            #pragma unroll
            for (int q = 0; q < 5; q++) {
                float4 wv = w4[q];
                s += wv.x * avr[q * 4 + 0] + wv.y * avr[q * 4 + 1]
                   + wv.z * avr[q * 4 + 2] + wv.w * avr[q * 4 + 3];
            }
            x0[r] = s;
        }
        if (b == 0 && t < 10) {
            float s = fc3b[t];
            for (int j = 0; j < 20; j++) s += fc3w[t * 20 + j] * avr[j];
            out[20670 + t] = s;
        }
    } else {
        int wv = (b - 216) * 4 + (t >> 6);
        int lane = t & 63;
        if (wv >= 8 * 100) return;
        int f = wv / 100, o = wv % 100;
        float s = 0.f;
        for (int j = lane; j < 400; j += 64) {
            float xv = (j < 200) ? pose200[f * 200 + j] : pose_feat[f * 200 + (j - 200)];
            s += xv * fc6w[o * 400 + j];
        }
        #pragma unroll
        for (int off = 32; off > 0; off >>= 1) s += __shfl_down(s, off, 64);
        if (lane == 0) t1[f * 100 + o] = s + fc6b[o];
    }
}

// ---------------------------------------------------------------------------
__global__ __launch_bounds__(256) void fc7_gcl3(
    const float* __restrict__ x0, const int* __restrict__ ai3,
    const float* __restrict__ av3, const float* __restrict__ gW3,
    const float* __restrict__ gb3, float* __restrict__ y3,
    const float* __restrict__ t1, const float* __restrict__ fc7w,
    const float* __restrict__ fc7b, const float* __restrict__ pose_mean,
    const float* __restrict__ trans, float* __restrict__ out)
{
    constexpr int F = 64, O = 32, N = 862;
    __shared__ float h[256];
    __shared__ float pp[256];
    const int b = blockIdx.x;
    const int wid = threadIdx.x >> 6, lane = threadIdx.x & 63;

    if (b < N) {
        const int n = b;
        {
            const int k = wid;
            const int*   ip = ai3 + ((size_t)k * N + n) * 16;
            const float* vp = av3 + ((size_t)k * N + n) * 16;
            float s = 0.f;
            #pragma unroll
            for (int d = 0; d < 16; d++)
                s += vp[d] * x0[(size_t)ip[d] * F + lane];
            h[k * F + lane] = s;
        }
        __syncthreads();
        const int t = threadIdx.x;
        const int o = t & 31, part = t >> 5;
        {
            float s = 0.f;
            const int base = part * 32;
            #pragma unroll 8
            for (int i = 0; i < 32; i++)
                s += h[base + i] * gW3[(size_t)(base + i) * O + o];
            pp[t] = s;
        }
        __syncthreads();
        if (t < O) {
            float s = gb3[t];
            #pragma unroll
            for (int p = 0; p < 8; p++) s += pp[p * O + t];
            y3[(size_t)n * O + t] = fmaxf(s, 0.f);
        }
    } else {
        int wv = (b - N) * 4 + wid;
        if (wv >= 8 * 219) return;
        int f = wv / 219, c = wv % 219;
        float s = t1[f * 100 + lane] * fc7w[c * 100 + lane];
        int j2 = lane + 64;
        if (j2 < 100) s += t1[f * 100 + j2] * fc7w[c * 100 + j2];
        #pragma unroll
        for (int off = 32; off > 0; off >>= 1) s += __shfl_down(s, off, 64);
        if (lane != 0) return;
        s += fc7b[c];
        float pct;
        if (c < 3) {
            pct = trans[c];
        } else {
            int j = (c - 3) / 9, e = (c - 3) % 9;
            float rx = (j == 0) ? 0.f : pose_mean[3 * j + 0];
            float ry = (j == 0) ? 0.f : pose_mean[3 * j + 1];
            float rz = (j == 0) ? 0.f : pose_mean[3 * j + 2];
            float th = sqrtf(rx * rx + ry * ry + rz * rz) + 1e-8f;
            float kx = rx / th, ky = ry / th, kz = rz / th;
            float sn = sinf(th), c2 = 1.f - cosf(th);
            float R[9];
            R[0] = 1.f - c2 * (ky * ky + kz * kz);
            R[1] = -sn * kz + c2 * (kx * ky);
            R[2] =  sn * ky + c2 * (kx * kz);
            R[3] =  sn * kz + c2 * (kx * ky);
            R[4] = 1.f - c2 * (kx * kx + kz * kz);
            R[5] = -sn * kx + c2 * (ky * kz);
            R[6] = -sn * ky + c2 * (kx * kz);
            R[7] =  sn * kx + c2 * (ky * kz);
            R[8] = 1.f - c2 * (kx * kx + ky * ky);
            pct = R[e];
        }
        s += pct;
        if (c < 3) out[22408 + f * 3 + c] = s;
        else       out[20680 + f * 216 + (c - 3)] = s;
    }
}

// ---------------------------------------------------------------------------
template<int F, int O, int ACT>
__global__ __launch_bounds__(256) void gcl(
    const float* __restrict__ x, const int* __restrict__ ai,
    const float* __restrict__ av, const float* __restrict__ gW,
    const float* __restrict__ gb, float* __restrict__ y, int N)
{
    constexpr int VPB = 64 / F;
    constexpr int OUTS = VPB * O;
    constexpr int PARTS = (256 / OUTS) >= 16 ? 16 :
                          ((256 / OUTS) >= 8 ? 8 :
                          ((256 / OUTS) >= 4 ? 4 : 2));
    constexpr int CH = 4 * F / PARTS;
    constexpr int HS = 4 * F + 4;
    __shared__ float h[VPB][HS];
    __shared__ float pp[OUTS * PARTS];

    const int k = threadIdx.x >> 6;
    const int lane = threadIdx.x & 63;
    const int vl = (VPB == 1) ? 0 : lane / F;
    const int fl = lane % F;
    const int n = blockIdx.x * VPB + vl;
    if (n < N) {
        const int*   ip = ai + ((size_t)k * N + n) * 16;
        const float* vp = av + ((size_t)k * N + n) * 16;
        float s = 0.f;
        #pragma unroll
        for (int d = 0; d < 16; d++)
            s += vp[d] * x[(size_t)ip[d] * F + fl];
        h[vl][k * F + fl] = s;
    }
    __syncthreads();

    const int t = threadIdx.x;
    if (t < OUTS * PARTS) {
        const int idx = t % OUTS;
        const int part = t / OUTS;
        const int v = idx / O, o = idx % O;
        float s = 0.f;
        const int base = part * CH;
        #pragma unroll
        for (int i = 0; i < CH; i++)
            s += h[v][base + i] * gW[(size_t)(base + i) * O + o];
        pp[part * OUTS + idx] = s;
    }
    __syncthreads();
    if (t < OUTS) {
        const int v = t / O, o = t % O;
        const int n2 = blockIdx.x * VPB + v;
        if (n2 < N) {
            float s = gb[o];
            #pragma unroll
            for (int p = 0; p < PARTS; p++) s += pp[p * OUTS + t];
            if (ACT == 0) s = fmaxf(s, 0.f);
            else          s = tanhf(s) * 0.1f;
            y[(size_t)n2 * O + o] = s;
        }
    }
}

template<int F>
__global__ __launch_bounds__(256) void spmm(
    const float* __restrict__ x, const int* __restrict__ ui,
    const float* __restrict__ uv, float* __restrict__ y, int N)
{
    int t = blockIdx.x * 256 + threadIdx.x;
    if (t >= N * F) return;
    int n = t / F, f = t % F;
    float s = 0.f;
    #pragma unroll
    for (int j = 0; j < 4; j++)
        s += uv[n * 4 + j] * x[(size_t)ui[n * 4 + j] * F + f];
    y[t] = s;
}

// ---------------------------------------------------------------------------
extern "C" void kernel_launch(void* const* d_in, const int* in_sizes, int n_in,
                              void* d_out, int out_size, void* d_ws, size_t ws_size,
                              hipStream_t stream) {
    (void)in_sizes; (void)n_in; (void)out_size; (void)ws_size;

    const float* seg   = (const float*)d_in[0];
    const float* poses = (const float*)d_in[1];
    const float* pmean = (const float*)d_in[2];
    const float* trans = (const float*)d_in[3];
    const float* c1w = (const float*)d_in[4];  const float* c1b = (const float*)d_in[5];
    const float* c2w = (const float*)d_in[6];  const float* c2b = (const float*)d_in[7];
    const float* c3w = (const float*)d_in[8];  const float* c3b = (const float*)d_in[9];
    const float* c4w = (const float*)d_in[10]; const float* c4b = (const float*)d_in[11];
    const float* c5w = (const float*)d_in[12]; const float* c5b = (const float*)d_in[13];
    const float* fc1w = (const float*)d_in[14]; const float* fc1b = (const float*)d_in[15];
    const float* fc2w = (const float*)d_in[16]; const float* fc2b = (const float*)d_in[17];
    const float* fc3w = (const float*)d_in[18]; const float* fc3b = (const float*)d_in[19];
    const float* fc4w = (const float*)d_in[20]; const float* fc4b = (const float*)d_in[21];
    const float* fc5w = (const float*)d_in[22]; const float* fc5b = (const float*)d_in[23];
    const float* fc6w = (const float*)d_in[24]; const float* fc6b = (const float*)d_in[25];
    const float* fc7w = (const float*)d_in[26]; const float* fc7b = (const float*)d_in[27];
    const float* gW3 = (const float*)d_in[28]; const float* gb3 = (const float*)d_in[29];
    const float* gW2 = (const float*)d_in[30]; const float* gb2 = (const float*)d_in[31];
    const float* gW1 = (const float*)d_in[32]; const float* gb1 = (const float*)d_in[33];
    const float* gW0 = (const float*)d_in[34]; const float* gb0 = (const float*)d_in[35];
    const float* av3 = (const float*)d_in[36]; const int* ai3 = (const int*)d_in[37];
    const float* av2 = (const float*)d_in[38]; const int* ai2 = (const int*)d_in[39];
    const float* av1 = (const float*)d_in[40]; const int* ai1 = (const int*)d_in[41];
    const float* av0 = (const float*)d_in[42]; const int* ai0 = (const int*)d_in[43];
    const float* uv2 = (const float*)d_in[44]; const int* ui2 = (const int*)d_in[45];
    const float* uv1 = (const float*)d_in[46]; const int* ui1 = (const int*)d_in[47];
    const float* uv0 = (const float*)d_in[48]; const int* ui0 = (const int*)d_in[49];

    float* W = (float*)d_ws;
    float* out = (float*)d_out;

    float* pool1 = W + 0;
    float* pool2 = W + 4129024;
    float* pool3 = W + 0;
    float* pool4 = W + 4129024;
    float* flat5 = W + 4589824;
    float* shape20 = W + 1000000;
    float* pose200 = shape20 + 160;
    float* x0  = pose200 + 1600;
    float* y3  = x0 + 55168;
    float* x2  = y3 + 27584;
    float* y2  = x2 + 55136;
    float* x1  = y2 + 27568;
    float* y1  = x1 + 55120;
    float* x0u = y1 + 55120;
    float* pose_feat = x0u + 110240;
    float* t1 = pose_feat + 1600;

    // conv backbone — z-splits halved (OCG doubled) to cut L2/L3 input
    // re-reads: conv3 65->32MB, conv4 126->63MB, conv5 118->59MB; all >=256 blocks
    conv1_lds<<<dim3(256, 8), 256, 0, stream>>>(seg, c1w, c1b, pool1);
    conv_pool_s1<8, 8, true, false>
        <<<dim3(63, 8, 2), 256, 0, stream>>>(pool1, c2w, c2b, pool2, 254, 126, 16);
    conv_pool_s1<16, 8, true, false>
        <<<dim3(16, 8, 4), 256, 0, stream>>>(pool2, c3w, c3b, pool3, 126, 62, 32);
    conv_pool_s1<32, 4, true, false>
        <<<dim3(4, 8, 16), 256, 0, stream>>>(pool3, c4w, c4b, pool4, 62, 30, 64);
    conv_pool_s1<64, 4, false, true>
        <<<dim3(1, 8, 32), 256, 0, stream>>>(pool4, c5w, c5b, flat5, 30, 14, 128);

    // heads
    fc_head_plus<<<dim3(227), 256, 0, stream>>>(flat5, fc1w, fc1b, fc4w, fc4b,
                                                poses, fc5w, fc5b,
                                                shape20, pose200, pose_feat);
    mid_fused<<<dim3(416), 256, 0, stream>>>(shape20, fc2w, fc2b, fc3w, fc3b, x0, out,
                                             pose200, pose_feat, fc6w, fc6b, t1);

    // tail (round-14 best structure)
    fc7_gcl3<<<dim3(1300), 256, 0, stream>>>(x0, ai3, av3, gW3, gb3, y3,
                                             t1, fc7w, fc7b, pmean, trans, out);
    spmm<32>      <<<dim3(216),  256, 0, stream>>>(y3,  ui2, uv2, x2, 1723);
    gcl<32, 16, 0><<<dim3(862),  256, 0, stream>>>(x2,  ai2, av2, gW2, gb2, y2, 1723);
    spmm<16>      <<<dim3(216),  256, 0, stream>>>(y2,  ui1, uv1, x1, 3445);
    gcl<16, 16, 0><<<dim3(862),  256, 0, stream>>>(x1,  ai1, av1, gW1, gb1, y1, 3445);
    spmm<16>      <<<dim3(431),  256, 0, stream>>>(y1,  ui0, uv0, x0u, 6890);
    gcl<16, 3, 1> <<<dim3(1723), 256, 0, stream>>>(x0u, ai0, av0, gW0, gb0, out, 6890);
}